// Round 12
// baseline (525.076 us; speedup 1.0000x reference)
//
#include <hip/hip_runtime.h>
#include <cmath>
#include <type_traits>

typedef __bf16 bf16;
typedef __attribute__((ext_vector_type(8))) __bf16 bf16x8;
typedef __attribute__((ext_vector_type(4))) __bf16 bf16x4;
typedef __attribute__((ext_vector_type(4))) float f32x4;

#define LOG2E 1.4426950408889634f

__device__ __forceinline__ unsigned f2s(float x) {
    unsigned u = __float_as_uint(x);
    return (u & 0x80000000u) ? ~u : (u | 0x80000000u);
}
__device__ __forceinline__ float s2f(unsigned s) {
    return (s & 0x80000000u) ? __uint_as_float(s & 0x7FFFFFFFu)
                             : __uint_as_float(~s);
}

// ---------------- combined weight prep + deg zero ----------------
__global__ void prep_weights_kernel(const float* __restrict__ W0, const float* __restrict__ W1,
                                    const float* __restrict__ W2, const float* __restrict__ rW2,
                                    bf16* __restrict__ Wt0, bf16* __restrict__ Wt1,
                                    bf16* __restrict__ Bct, int* __restrict__ deg, int N) {
    const int idx = blockIdx.x * blockDim.x + threadIdx.x;
    if (idx < 65536) {
        const int k = idx >> 8, m = idx & 255;
        Wt0[m * 256 + k] = (bf16)W0[idx];
        Wt1[m * 256 + k] = (bf16)W1[idx];
    }
    if (idx < 8192) {
        const int m = idx >> 8, k = idx & 255;
        const float v = (m < 16) ? W2[k * 16 + m] : rW2[k * 16 + (m - 16)];
        Bct[idx] = (bf16)v;
    }
    if (idx < N) deg[idx] = 0;
}

// ---------------- cast x fp32 -> bf16 ----------------
__global__ void cast_x_kernel(const float* __restrict__ x, bf16* __restrict__ xb, long total8) {
    const long t = (long)blockIdx.x * blockDim.x + threadIdx.x;
    if (t >= total8) return;
    const float4* xp = (const float4*)x + t * 2;
    const float4 f0 = xp[0], f1 = xp[1];
    bf16x8 o;
    o[0] = (bf16)f0.x; o[1] = (bf16)f0.y; o[2] = (bf16)f0.z; o[3] = (bf16)f0.w;
    o[4] = (bf16)f1.x; o[5] = (bf16)f1.y; o[6] = (bf16)f1.z; o[7] = (bf16)f1.w;
    ((bf16x8*)xb)[t] = o;
}

// ---------------- MFMA GEMM: Fb[N,256](bf16) = A[N,256](bf16) @ B (Bt bf16) ----
__global__ __launch_bounds__(256) void gemm_mfma_bf16(const bf16* __restrict__ A,
                                                      const bf16* __restrict__ Bt,
                                                      bf16* __restrict__ Fb, int N) {
    constexpr int K = 256, BM = 128, BK = 32;
    constexpr int LDA = BK + 8;
    __shared__ bf16 As[BM * LDA];
    __shared__ bf16 Bs[BM * LDA];

    const int tid = threadIdx.x;
    const int wave = tid >> 6, lane = tid & 63;
    const int quad = lane >> 4, l16 = lane & 15;
    const int rowBase = blockIdx.y * BM;
    const int colBase = blockIdx.x * BM;
    const int m_base = (wave >> 1) * 64, n_base = (wave & 1) * 64;

    f32x4 acc[4][4] = {};

    const int sr = tid >> 1;
    const int seg = (tid & 1) << 4;

    for (int k0 = 0; k0 < K; k0 += BK) {
        {
            const int gr = rowBase + sr;
            bf16x8 p0 = {}, p1 = {};
            if (gr < N) {
                const bf16x8* Ag = (const bf16x8*)(A + (long)gr * K + k0 + seg);
                p0 = Ag[0]; p1 = Ag[1];
            }
            *(bf16x8*)&As[sr * LDA + seg] = p0;
            *(bf16x8*)&As[sr * LDA + seg + 8] = p1;
        }
        {
            const bf16x8* Bg = (const bf16x8*)(Bt + (long)(colBase + sr) * K + k0 + seg);
            *(bf16x8*)&Bs[sr * LDA + seg] = Bg[0];
            *(bf16x8*)&Bs[sr * LDA + seg + 8] = Bg[1];
        }
        __syncthreads();

        bf16x8 af[4], bfr[4];
#pragma unroll
        for (int mi = 0; mi < 4; mi++)
            af[mi] = *(const bf16x8*)&As[(m_base + mi * 16 + l16) * LDA + quad * 8];
#pragma unroll
        for (int ni = 0; ni < 4; ni++)
            bfr[ni] = *(const bf16x8*)&Bs[(n_base + ni * 16 + l16) * LDA + quad * 8];
#pragma unroll
        for (int mi = 0; mi < 4; mi++)
#pragma unroll
            for (int ni = 0; ni < 4; ni++)
                acc[mi][ni] = __builtin_amdgcn_mfma_f32_16x16x32_bf16(af[mi], bfr[ni], acc[mi][ni], 0, 0, 0);
        __syncthreads();
    }

    // epilogue: C/D layout col=lane&15, row=quad*4+reg [m89-verified]; write bf16
#pragma unroll
    for (int mi = 0; mi < 4; mi++) {
#pragma unroll
        for (int r = 0; r < 4; r++) {
            const int grow = rowBase + m_base + mi * 16 + quad * 4 + r;
            if (grow < N) {
#pragma unroll
                for (int ni = 0; ni < 4; ni++) {
                    Fb[(long)grow * 256 + colBase + n_base + ni * 16 + l16] = (bf16)acc[mi][ni][r];
                }
            }
        }
    }
}

// ---------------- MFMA GEMM narrow: C[N,32](fp32) = A[N,256](bf16) @ Bct^T --------
__global__ __launch_bounds__(256) void gemm_mfma_n32(const bf16* __restrict__ A,
                                                     const bf16* __restrict__ Bt,
                                                     float* __restrict__ C, int N) {
    constexpr int K = 256, BM = 128, BK = 32;
    constexpr int LDA = BK + 8;
    __shared__ bf16 As[BM * LDA];
    __shared__ bf16 Bs[32 * LDA];

    const int tid = threadIdx.x;
    const int wave = tid >> 6, lane = tid & 63;
    const int quad = lane >> 4, l16 = lane & 15;
    const int rowBase = blockIdx.x * BM;
    const int m_base = (wave >> 1) * 64, n_base = (wave & 1) * 16;

    f32x4 acc[4] = {};

    const int sr = tid >> 1;
    const int seg = (tid & 1) << 4;

    for (int k0 = 0; k0 < K; k0 += BK) {
        {
            const int gr = rowBase + sr;
            bf16x8 p0 = {}, p1 = {};
            if (gr < N) {
                const bf16x8* Ag = (const bf16x8*)(A + (long)gr * K + k0 + seg);
                p0 = Ag[0]; p1 = Ag[1];
            }
            *(bf16x8*)&As[sr * LDA + seg] = p0;
            *(bf16x8*)&As[sr * LDA + seg + 8] = p1;
        }
        if (tid < 64) {
            const int br = tid >> 1;
            const bf16x8* Bg = (const bf16x8*)(Bt + br * K + k0 + seg);
            *(bf16x8*)&Bs[br * LDA + seg] = Bg[0];
            *(bf16x8*)&Bs[br * LDA + seg + 8] = Bg[1];
        }
        __syncthreads();

        const bf16x8 bfr = *(const bf16x8*)&Bs[(n_base + l16) * LDA + quad * 8];
#pragma unroll
        for (int mi = 0; mi < 4; mi++) {
            const bf16x8 af = *(const bf16x8*)&As[(m_base + mi * 16 + l16) * LDA + quad * 8];
            acc[mi] = __builtin_amdgcn_mfma_f32_16x16x32_bf16(af, bfr, acc[mi], 0, 0, 0);
        }
        __syncthreads();
    }

#pragma unroll
    for (int mi = 0; mi < 4; mi++) {
#pragma unroll
        for (int r = 0; r < 4; r++) {
            const int grow = rowBase + m_base + mi * 16 + quad * 4 + r;
            if (grow < N) C[(long)grow * 32 + n_base + l16] = acc[mi][r];
        }
    }
}

// ---------------- el/er (scaled by log2e) + fused elmax, grid-stride ----------------
// One wave per node per iter; outputs el/er in log2 domain. Per-block max -> 4 atomics.
__global__ void el_er_fused(const bf16* __restrict__ feat,
                            const float* __restrict__ al, const float* __restrict__ ar,
                            float* __restrict__ el, float* __restrict__ er,
                            unsigned* __restrict__ elmax_u, int N) {
    __shared__ float smax[16];     // 4 waves x 4 heads
    const int wave = threadIdx.x >> 6;
    const int lane = threadIdx.x & 63;
    const int h = lane >> 4;
    float4 a = ((const float4*)al)[lane];
    float4 b = ((const float4*)ar)[lane];
    a.x *= LOG2E; a.y *= LOG2E; a.z *= LOG2E; a.w *= LOG2E;
    b.x *= LOG2E; b.y *= LOG2E; b.z *= LOG2E; b.w *= LOG2E;
    const int nwaves = (gridDim.x * blockDim.x) >> 6;
    float mloc = -INFINITY;
    for (int wid = (blockIdx.x * blockDim.x + threadIdx.x) >> 6; wid < N; wid += nwaves) {
        const bf16x4 f = ((const bf16x4*)feat)[(long)wid * 64 + lane];
        const float f0 = (float)f[0], f1 = (float)f[1], f2 = (float)f[2], f3 = (float)f[3];
        float vl = f0 * a.x + f1 * a.y + f2 * a.z + f3 * a.w;
        float vr = f0 * b.x + f1 * b.y + f2 * b.z + f3 * b.w;
#pragma unroll
        for (int off = 1; off < 16; off <<= 1) {
            vl += __shfl_xor(vl, off);
            vr += __shfl_xor(vr, off);
        }
        if ((lane & 15) == 0) {
            el[wid * 4 + h] = vl;
            er[wid * 4 + h] = vr;
            mloc = fmaxf(mloc, vl);
        }
    }
    if ((lane & 15) == 0) smax[wave * 4 + h] = mloc;
    __syncthreads();
    if (threadIdx.x < 4) {
        const float m = fmaxf(fmaxf(smax[threadIdx.x], smax[4 + threadIdx.x]),
                              fmaxf(smax[8 + threadIdx.x], smax[12 + threadIdx.x]));
        atomicMax(&elmax_u[threadIdx.x], f2s(m));
    }
}

// layer 2 (H=1, D=16): 4 nodes per wave; scaled + fused max into elmax_u[8]
__global__ void el_er2_fused(const float* __restrict__ F2,
                             const float* __restrict__ al2, const float* __restrict__ ar2,
                             float* __restrict__ el, float* __restrict__ er,
                             unsigned* __restrict__ elmax_u, int N) {
    __shared__ float smax[4];
    const int wave = threadIdx.x >> 6;
    const int lane = threadIdx.x & 63;
    const int sub = lane >> 4;
    const int c = lane & 15;
    const float a = al2[c] * LOG2E;
    const float b = ar2[c] * LOG2E;
    const int nwaves = (gridDim.x * blockDim.x) >> 6;
    float mloc = -INFINITY;
    for (int q = (blockIdx.x * blockDim.x + threadIdx.x) >> 6; q * 4 < N; q += nwaves) {
        const int n = q * 4 + sub;
        float vl = 0.f, vr = 0.f;
        if (n < N) {
            const float f = F2[(long)n * 32 + c];
            vl = f * a; vr = f * b;
        }
#pragma unroll
        for (int off = 1; off < 16; off <<= 1) {
            vl += __shfl_xor(vl, off);
            vr += __shfl_xor(vr, off);
        }
        if (c == 0 && n < N) {
            el[n] = vl; er[n] = vr;
            mloc = fmaxf(mloc, vl);
        }
    }
    mloc = fmaxf(mloc, __shfl_xor(mloc, 16));
    mloc = fmaxf(mloc, __shfl_xor(mloc, 32));
    if (lane == 0) smax[wave] = mloc;
    __syncthreads();
    if (threadIdx.x == 0) {
        const float m = fmaxf(fmaxf(smax[0], smax[1]), fmaxf(smax[2], smax[3]));
        atomicMax(&elmax_u[8], f2s(m));
    }
}

// ---------------- CSR build ----------------

__global__ void count_deg_kernel(const int* __restrict__ dst, int* __restrict__ deg, int E) {
    const int e = blockIdx.x * blockDim.x + threadIdx.x;
    if (e >= E) return;
    atomicAdd(&deg[dst[e]], 1);
}

__global__ void scan_block_kernel(const int* __restrict__ deg, int* __restrict__ scanned,
                                  int* __restrict__ block_sums, int N) {
    __shared__ int smem[256];
    const int tid = threadIdx.x;
    const int base = blockIdx.x * 1024 + tid * 4;
    int v[4];
#pragma unroll
    for (int i = 0; i < 4; i++) v[i] = (base + i < N) ? deg[base + i] : 0;
    const int tsum = v[0] + v[1] + v[2] + v[3];
    smem[tid] = tsum;
    __syncthreads();
    int acc = tsum;
    for (int off = 1; off < 256; off <<= 1) {
        const int t = (tid >= off) ? smem[tid - off] : 0;
        __syncthreads();
        acc += t;
        smem[tid] = acc;
        __syncthreads();
    }
    if (tid == 255) block_sums[blockIdx.x] = acc;
    int run = acc - tsum;
#pragma unroll
    for (int i = 0; i < 4; i++) {
        if (base + i < N) scanned[base + i] = run;
        run += v[i];
    }
}

__global__ void scan_sums_kernel(int* __restrict__ block_sums, unsigned* __restrict__ elmax_u, int nb) {
    const int tid = threadIdx.x;
    if (tid < 12) elmax_u[tid] = f2s(-INFINITY);
    const int orig = (tid < nb) ? block_sums[tid] : 0;
    int v = orig;
#pragma unroll
    for (int off = 1; off < 64; off <<= 1) {
        const int t = __shfl_up(v, off);
        if (tid >= off) v += t;
    }
    if (tid < nb) block_sums[tid] = v - orig;
}

__global__ void apply_offsets_kernel(const int* __restrict__ scanned, const int* __restrict__ block_sums,
                                     int* __restrict__ row_ptr, int* __restrict__ cursor, int N, int E) {
    const int i = blockIdx.x * blockDim.x + threadIdx.x;
    if (i < N) {
        const int v = scanned[i] + block_sums[i >> 10];
        row_ptr[i] = v;
        cursor[i] = v;
    }
    if (i == 0) row_ptr[N] = E;
}

__global__ void scatter_kernel(const int* __restrict__ src, const int* __restrict__ dst,
                               int* __restrict__ cursor, int* __restrict__ csr_src, int E) {
    const int e = blockIdx.x * blockDim.x + threadIdx.x;
    if (e >= E) return;
    const int pos = atomicAdd(&cursor[dst[e]], 1);
    csr_src[pos] = src[e];
}

// ---------------- aggregate: TWO nodes per wave (32 lanes x bf16x8 each) ----------
// Inline softmax in log2 domain: w = exp2(leaky(el+erd) - shift), shift =
// leaky(elmax + erd) >= e (leaky monotonic, positively homogeneous) => w <= 1,
// softmax ratio identical to reference. el/er pre-scaled by log2(e).
template <bool ACT>
__global__ void gat_aggregate_wave2(const int* __restrict__ row_ptr, const int* __restrict__ csr_src,
                                    const float* __restrict__ el, const float* __restrict__ er,
                                    const unsigned* __restrict__ elmax_u,
                                    const bf16* __restrict__ feat,
                                    const bf16* __restrict__ res, const float* __restrict__ bias,
                                    bf16* __restrict__ out, int N, int E) {
    const int wave = threadIdx.x >> 6;
    const int lane = threadIdx.x & 63;
    const int half = lane >> 5;        // 0 = node A, 1 = node B
    const int li   = lane & 31;        // 32 lanes x 16B = 512B row
    const int h    = li >> 3;          // 8 lanes per head (D=64, 8 ch/lane)
    int nA = (blockIdx.x * (blockDim.x >> 6) + wave) * 2;
    if (nA >= N) return;
    nA = __builtin_amdgcn_readfirstlane(nA);
    const int nB = nA + 1;
    const bool haveB = (nB < N);
    const int n = half ? (haveB ? nB : nA) : nA;

    const float erd = er[n * 4 + h];
    float sh = s2f(elmax_u[h]) + erd;
    sh = fmaxf(sh, 0.2f * sh);

    const int pA0 = row_ptr[nA];
    const int pA1 = row_ptr[nA + 1];
    const int pB0 = haveB ? row_ptr[nB] : 0;
    const int pB1 = haveB ? row_ptr[nB + 1] : 0;
    const int degA = pA1 - pA0, degB = pB1 - pB0;
    const int steps = (degA > degB) ? degA : degB;
    const int deg = half ? degB : degA;

    const bf16x8* feat8 = (const bf16x8*)feat;
    float acc[8] = {};
    float l = 0.f;

    int i = 0;
    for (; i + 2 <= steps; i += 2) {
        const int iA0 = min(pA0 + i, E - 1);
        const int iB0 = min(pB0 + i, E - 1);
        const int iA1 = min(pA0 + i + 1, E - 1);
        const int iB1 = min(pB0 + i + 1, E - 1);
        const int sA0 = csr_src[iA0], sB0 = csr_src[iB0];
        const int sA1 = csr_src[iA1], sB1 = csr_src[iB1];
        const int s0 = half ? sB0 : sA0;
        const int s1 = half ? sB1 : sA1;
        float e0 = el[s0 * 4 + h] + erd;
        float e1 = el[s1 * 4 + h] + erd;
        e0 = fmaxf(e0, 0.2f * e0);
        e1 = fmaxf(e1, 0.2f * e1);
        float w0 = exp2f(e0 - sh);
        float w1 = exp2f(e1 - sh);
        w0 = (i < deg) ? w0 : 0.f;
        w1 = (i + 1 < deg) ? w1 : 0.f;
        const bf16x8 f0 = feat8[(long)s0 * 32 + li];
        const bf16x8 f1 = feat8[(long)s1 * 32 + li];
        l += w0 + w1;
#pragma unroll
        for (int j = 0; j < 8; j++) acc[j] += w0 * (float)f0[j] + w1 * (float)f1[j];
    }
    for (; i < steps; ++i) {
        const int iA = min(pA0 + i, E - 1);
        const int iB = min(pB0 + i, E - 1);
        const int sA = csr_src[iA], sB = csr_src[iB];
        const int s = half ? sB : sA;
        float e = el[s * 4 + h] + erd;
        e = fmaxf(e, 0.2f * e);
        float w = exp2f(e - sh);
        w = (i < deg) ? w : 0.f;
        const bf16x8 f = feat8[(long)s * 32 + li];
        l += w;
#pragma unroll
        for (int j = 0; j < 8; j++) acc[j] += w * (float)f[j];
    }
    const float inv = (l > 0.f) ? 1.f / l : 0.f;

    const bf16x8 rb = ((const bf16x8*)res)[(long)n * 32 + li];
    const float4 bb0 = ((const float4*)bias)[li * 2];
    const float4 bb1 = ((const float4*)bias)[li * 2 + 1];
    float v[8];
    v[0] = acc[0] * inv + (float)rb[0] + bb0.x;
    v[1] = acc[1] * inv + (float)rb[1] + bb0.y;
    v[2] = acc[2] * inv + (float)rb[2] + bb0.z;
    v[3] = acc[3] * inv + (float)rb[3] + bb0.w;
    v[4] = acc[4] * inv + (float)rb[4] + bb1.x;
    v[5] = acc[5] * inv + (float)rb[5] + bb1.y;
    v[6] = acc[6] * inv + (float)rb[6] + bb1.z;
    v[7] = acc[7] * inv + (float)rb[7] + bb1.w;
    if (ACT) {
#pragma unroll
        for (int j = 0; j < 8; j++) {
            const float sp = (v[j] > 20.f) ? v[j] : log1pf(expf(v[j]));
            v[j] = v[j] * tanhf(sp);
        }
    }
    if (half == 0 || haveB) {
        bf16x8 o;
#pragma unroll
        for (int j = 0; j < 8; j++) o[j] = (bf16)v[j];
        ((bf16x8*)out)[(long)n * 32 + li] = o;
    }
}

// ---------------- small-C aggregate (layer 2) + inline exp2 weights --------------
template <bool ACT, int NPB>
__global__ void gat_aggregate_small(const int* __restrict__ row_ptr, const int* __restrict__ csr_src,
                                    const float* __restrict__ el, const float* __restrict__ er,
                                    const unsigned* __restrict__ elmax_u,
                                    const float* __restrict__ feat, int fstride,
                                    const float* __restrict__ res, int rstride,
                                    const float* __restrict__ bias, float* __restrict__ out, int N) {
    constexpr int C = 16;
    const int local = threadIdx.x % C;
    const int n = blockIdx.x * NPB + threadIdx.x / C;
    if (n >= N) return;
    const float mx = s2f(elmax_u[8]);
    const float erd = er[n];
    float sh = mx + erd;
    sh = fmaxf(sh, 0.2f * sh);

    float acc = 0.f, l = 0.f;
    int p = row_ptr[n];
    const int pend = row_ptr[n + 1];
    for (; p + 4 <= pend; p += 4) {
        const int s0 = csr_src[p + 0];
        const int s1 = csr_src[p + 1];
        const int s2 = csr_src[p + 2];
        const int s3 = csr_src[p + 3];
        float e0 = el[s0] + erd, e1 = el[s1] + erd, e2 = el[s2] + erd, e3 = el[s3] + erd;
        e0 = fmaxf(e0, 0.2f * e0);
        e1 = fmaxf(e1, 0.2f * e1);
        e2 = fmaxf(e2, 0.2f * e2);
        e3 = fmaxf(e3, 0.2f * e3);
        const float w0 = exp2f(e0 - sh);
        const float w1 = exp2f(e1 - sh);
        const float w2 = exp2f(e2 - sh);
        const float w3 = exp2f(e3 - sh);
        l += w0 + w1 + w2 + w3;
        acc += w0 * feat[(long)s0 * fstride + local] + w1 * feat[(long)s1 * fstride + local]
             + w2 * feat[(long)s2 * fstride + local] + w3 * feat[(long)s3 * fstride + local];
    }
    for (; p < pend; ++p) {
        const int s = csr_src[p];
        float e = el[s] + erd;
        e = fmaxf(e, 0.2f * e);
        const float w = exp2f(e - sh);
        l += w;
        acc += w * feat[(long)s * fstride + local];
    }
    const float inv = (l > 0.f) ? 1.f / l : 0.f;
    float v = acc * inv + res[(long)n * rstride + local] + bias[local];
    if (ACT) {
        const float sp = (v > 20.f) ? v : log1pf(expf(v));
        v = v * tanhf(sp);
    }
    out[(long)n * C + local] = v;
}

// ---------------- host orchestration ----------------

static inline int cdiv(long a, long b) { return (int)((a + b - 1) / b); }

extern "C" void kernel_launch(void* const* d_in, const int* in_sizes, int n_in,
                              void* d_out, int out_size, void* d_ws, size_t ws_size,
                              hipStream_t stream) {
    const float* x   = (const float*)d_in[0];
    const int*   src = (const int*)d_in[1];
    const int*   dst = (const int*)d_in[2];
    const float* W0  = (const float*)d_in[3];
    const float* al0 = (const float*)d_in[4];
    const float* ar0 = (const float*)d_in[5];
    const float* b0  = (const float*)d_in[6];
    const float* W1  = (const float*)d_in[7];
    const float* al1 = (const float*)d_in[8];
    const float* ar1 = (const float*)d_in[9];
    const float* b1  = (const float*)d_in[10];
    const float* W2  = (const float*)d_in[11];
    const float* al2 = (const float*)d_in[12];
    const float* ar2 = (const float*)d_in[13];
    const float* b2  = (const float*)d_in[14];
    const float* rW2 = (const float*)d_in[15];
    float* out = (float*)d_out;

    const int N = in_sizes[0] / 256;   // 50000
    const int E = in_sizes[1];         // 800000

    // workspace layout
    bf16* Wt0    = (bf16*)d_ws;               // 256*256 bf16
    bf16* Wt1    = Wt0 + 65536;               // 256*256 bf16
    bf16* Bct    = Wt1 + 65536;               // 32*256 bf16
    bf16* xb     = Bct + 8192;                // N*256 bf16 (x cast)
    bf16* Fb     = xb + (long)N * 256;        // N*256 bf16 feat
    bf16* Hb     = Fb + (long)N * 256;        // N*256 bf16 hidden
    float* F2    = (float*)(Hb + (long)N * 256);  // N*32 (layer2 feat | res)
    float* el    = F2 + (long)N * 32;         // N*4
    float* er    = el + (long)N * 4;          // N*4
    unsigned* elmax_u = (unsigned*)(er + (long)N * 4); // 12
    int* deg     = (int*)(elmax_u + 12);      // N
    int* scanned = deg + N;                   // N
    int* bsums   = scanned + N;               // 64
    int* row_ptr = bsums + 64;                // N+1
    int* cursor  = row_ptr + N + 1;           // N
    int* csr_src = cursor + N;                // E

    const int THREADS = 256;
    const int NB = cdiv(N, 1024);
    dim3 mfma_grid(2, cdiv(N, 128));

    // ---------- prep (+deg zero) + cast x + CSR build ----------
    prep_weights_kernel<<<cdiv(65536, THREADS), THREADS, 0, stream>>>(W0, W1, W2, rW2, Wt0, Wt1, Bct, deg, N);
    cast_x_kernel<<<cdiv((long)N * 32, THREADS), THREADS, 0, stream>>>(x, xb, (long)N * 32);
    count_deg_kernel<<<cdiv(E, THREADS), THREADS, 0, stream>>>(dst, deg, E);
    scan_block_kernel<<<NB, 256, 0, stream>>>(deg, scanned, bsums, N);
    scan_sums_kernel<<<1, 64, 0, stream>>>(bsums, elmax_u, NB);
    apply_offsets_kernel<<<cdiv(N, THREADS), THREADS, 0, stream>>>(scanned, bsums, row_ptr, cursor, N, E);
    scatter_kernel<<<cdiv(E, THREADS), THREADS, 0, stream>>>(src, dst, cursor, csr_src, E);

    // ================= Layer 0 (H=4, D=64): in xb (bf16), out Hb (bf16) ===========
    gemm_mfma_bf16<<<mfma_grid, 256, 0, stream>>>(xb, Wt0, Fb, N);
    el_er_fused<<<256, 256, 0, stream>>>(Fb, al0, ar0, el, er, elmax_u, N);
    gat_aggregate_wave2<true><<<cdiv(N, 8), 256, 0, stream>>>(
        row_ptr, csr_src, el, er, elmax_u, Fb, xb, b0, Hb, N, E);

    // ================= Layer 1 (H=4, D=64): Hb -> Hb ==============================
    gemm_mfma_bf16<<<mfma_grid, 256, 0, stream>>>(Hb, Wt1, Fb, N);
    el_er_fused<<<256, 256, 0, stream>>>(Fb, al1, ar1, el, er, elmax_u + 4, N);
    gat_aggregate_wave2<true><<<cdiv(N, 8), 256, 0, stream>>>(
        row_ptr, csr_src, el, er, elmax_u + 4, Fb, Hb, b1, Hb, N, E);

    // ================= Layer 2 (H=1, D=16): F2 = Hb @ [W2|rW2] =====================
    gemm_mfma_n32<<<cdiv(N, 128), 256, 0, stream>>>(Hb, Bct, F2, N);
    el_er2_fused<<<128, 256, 0, stream>>>(F2, al2, ar2, el, er, elmax_u, N);
    gat_aggregate_small<false, 16><<<cdiv(N, 16), 256, 0, stream>>>(row_ptr, csr_src, el, er, elmax_u,
                                                                    F2, 32, F2 + 16, 32, b2, out, N);
}